// Round 15
// baseline (189.161 us; speedup 1.0000x reference)
//
#include <hip/hip_runtime.h>
#include <math.h>

#define NCLS    80
#define MTGT    100
#define NANCH   19200   // 3*80*80
#define BATCH   8
#define BLKA    64                  // anchors per block
#define NBLK    (NANCH / BLKA)      // 300 blocks per image
#define NWAVE   4
#define TSLICE  (MTGT / NWAVE)      // 25 targets per wave
#define ROW4    (NCLS / 4)          // 20 float4 per class row
#define NPART   (NBLK * BATCH)      // 2400 blocks total

__device__ __forceinline__ float fast_rcp(float x) { return __builtin_amdgcn_rcpf(x); }

// focal-loss contribution of one class logit x (matches reference formula exactly)
__device__ __forceinline__ float focal_term(float x, bool is_t) {
    const float ax  = fabsf(x);
    const float q   = __expf(-ax);                        // e^{-|x|} in (0,1]
    const float ce0 = fmaxf(x, 0.0f) + __logf(1.0f + q);  // softplus(x) = ce for onehot=0
    const float r   = fast_rcp(1.0f + q);
    const float p   = (x >= 0.0f) ? r : q * r;            // sigmoid(x)
    const float pt  = is_t ? (1.0f - p) : p;              // 1 - p_t
    const float ce  = is_t ? (ce0 - x) : ce0;
    const float at  = is_t ? 0.25f : 0.75f;
    return at * pt * pt * ce;
}

// Single pass, NO fences: phases A-C identical to the round-12 winner; block
// results go to per-image global atomic accumulators (coherent at LLC); the
// last-finished block (ws counter election, ordered by s_waitcnt on the atomic
// acks) reads accums with atomic reads and applies the reference formula.
__global__ __launch_bounds__(256) void anchor_kernel(
    const float* __restrict__ obj, const float* __restrict__ boxes,
    const float* __restrict__ cls, const float* __restrict__ tb,
    const int* __restrict__ tl, float* __restrict__ accums,
    unsigned int* __restrict__ counter, float* __restrict__ out)
{
    __shared__ float4 t_box[MTGT];    // (lo.x, lo.y, hi.x, hi.y)
    __shared__ float  t_area[MTGT];
    __shared__ int    t_lab[MTGT];
    __shared__ float  m_bi[NWAVE][BLKA];
    __shared__ float  m_bu[NWAVE][BLKA];
    __shared__ int    m_ix[NWAVE][BLKA];
    __shared__ float  s_posf[BLKA];
    __shared__ int    s_lab[BLKA];
    __shared__ float  s_foc[NWAVE];
    __shared__ float  s_bpb[3];       // wave0's reduced {bce, pos, bbox}
    __shared__ float  s_acc[32];
    __shared__ bool   s_last;

    const int b    = blockIdx.y;
    const int tid  = threadIdx.x;
    const int wave = tid >> 6;
    const int lane = tid & 63;

    if (tid < MTGT) {
        const float4 t = ((const float4*)tb)[b * MTGT + tid];
        t_box[tid]  = make_float4(t.x - 0.5f * t.z, t.y - 0.5f * t.w,
                                  t.x + 0.5f * t.z, t.y + 0.5f * t.w);
        t_area[tid] = t.z * t.w;
        t_lab[tid]  = tl[b * MTGT + tid];
    }
    __syncthreads();

    const int a0  = blockIdx.x * BLKA;         // first anchor of this block
    const int gid = b * NANCH + a0 + lane;

    const float4 bx = ((const float4*)boxes)[gid];
    const float lox = bx.x - 0.5f * bx.z, loy = bx.y - 0.5f * bx.w;
    const float hix = bx.x + 0.5f * bx.z, hiy = bx.y + 0.5f * bx.w;
    const float a1  = bx.z * bx.w;
    const float aa  = a1 + 1e-6f;              // fold union eps

    // phase A: rcp-free first-max argmax over this wave's target slice
    // iou_m > iou_best  <=>  inter_m*uni_best > inter_best*uni_m  (uni>0)
    float bi = -1.0f, bu = 1.0f; int bidx = 0;
    const int m0 = wave * TSLICE;
    #pragma unroll
    for (int mm = 0; mm < TSLICE; ++mm) {
        const int m = m0 + mm;
        const float4 t = t_box[m];
        float iw = fmaxf(fminf(hix, t.z) - fmaxf(lox, t.x), 0.0f);
        float ih = fmaxf(fminf(hiy, t.w) - fmaxf(loy, t.y), 0.0f);
        float inter = iw * ih;
        float uni   = aa + t_area[m] - inter;
        if (inter * bu > bi * uni) { bi = inter; bu = uni; bidx = m; }
    }
    m_bi[wave][lane] = bi;
    m_bu[wave][lane] = bu;
    m_ix[wave][lane] = bidx;
    __syncthreads();

    // phase B (wave 0): merge in ascending wave order (first-max preserved),
    // pos/BCE/GIoU, publish posf+label, reduce {bce,pos,bbox}
    if (wave == 0) {
        float Bi = m_bi[0][lane], Bu = m_bu[0][lane]; int Bx = m_ix[0][lane];
        #pragma unroll
        for (int w = 1; w < NWAVE; ++w) {
            const float ci = m_bi[w][lane], cu = m_bu[w][lane];
            if (ci * Bu > Bi * cu) { Bi = ci; Bu = cu; Bx = m_ix[w][lane]; }
        }

        const bool  pos  = (Bi + Bi >= Bu);   // iou >= 0.5 (Bu = uni + 1e-6)
        const float posf = pos ? 1.0f : 0.0f;
        s_posf[lane] = posf;
        s_lab[lane]  = t_lab[Bx];

        const float o   = obj[gid];
        const float bce = -fmaxf(__logf(pos ? o : 1.0f - o), -100.0f);

        float bbox_l = 0.0f;
        if (pos) {
            const float4 t   = t_box[Bx];
            const float uni  = a1 + t_area[Bx] - Bi;      // reference union (no eps)
            const float iou  = Bi * fast_rcp(Bu);
            const float ew   = fmaxf(fmaxf(hix, t.z) - fminf(lox, t.x), 0.0f);
            const float eh   = fmaxf(fmaxf(hiy, t.w) - fminf(loy, t.y), 0.0f);
            const float enc  = ew * eh;
            const float giou = iou - (enc - uni) * fast_rcp(enc + 1e-6f);
            bbox_l = 1.0f - giou;
        }

        float v0 = bce, v1 = posf, v2 = bbox_l;
        #pragma unroll
        for (int off = 32; off; off >>= 1) {
            v0 += __shfl_down(v0, off);
            v1 += __shfl_down(v1, off);
            v2 += __shfl_down(v2, off);
        }
        if (lane == 0) { s_bpb[0] = v0; s_bpb[1] = v1; s_bpb[2] = v2; }
    }
    __syncthreads();

    // phase C (all waves): cooperative focal. 64 anchors x 20 float4 = 1280
    // chunks flat across 256 threads x 5 iters; consecutive tids -> consecutive
    // 16-B addresses (coalesced). Negative anchors skipped via exec mask.
    float focal = 0.0f;
    #pragma unroll
    for (int k = 0; k < 5; ++k) {
        const int flat = k * 256 + tid;
        const int a    = flat / ROW4;          // anchor within block (0..63)
        const int j4   = flat - a * ROW4;      // float4 index within row (0..19)
        const float pf = s_posf[a];
        if (pf != 0.0f) {
            const int c = s_lab[a];
            const float4 v = *(const float4*)(cls +
                ((long)(b * NANCH + a0 + a)) * NCLS + j4 * 4);
            focal += focal_term(v.x, 4 * j4 + 0 == c)
                   + focal_term(v.y, 4 * j4 + 1 == c)
                   + focal_term(v.z, 4 * j4 + 2 == c)
                   + focal_term(v.w, 4 * j4 + 3 == c);
        }
    }
    #pragma unroll
    for (int off = 32; off; off >>= 1)
        focal += __shfl_down(focal, off);
    if (lane == 0) s_foc[wave] = focal;
    __syncthreads();

    // accumulate into per-image global accums (atomics: coherent, no fence),
    // then elect the last block. s_waitcnt vmcnt(0) orders our atomic acks
    // before the counter increment (cheap wait; NOT an L2 writeback).
    if (tid == 0) {
        atomicAdd(&accums[b * 4 + 0], s_bpb[0]);
        atomicAdd(&accums[b * 4 + 1], s_bpb[1]);
        atomicAdd(&accums[b * 4 + 2], s_bpb[2]);
        atomicAdd(&accums[b * 4 + 3], s_foc[0] + s_foc[1] + s_foc[2] + s_foc[3]);
        asm volatile("s_waitcnt vmcnt(0)" ::: "memory");
        const unsigned old = atomicAdd(counter, 1u);
        s_last = (old == (unsigned)(NPART - 1));
    }
    __syncthreads();
    if (!s_last) return;

    // final block: atomic reads of the 32 accums (bypass possibly-stale L2)
    if (wave == 0 && lane < 32)
        s_acc[lane] = atomicAdd(&accums[lane], 0.0f);
    __syncthreads();
    if (tid == 0) {
        float sum_pc = 0.f, obj_l = 0.f, bbox_s = 0.f, cls_l = 0.f;
        #pragma unroll
        for (int ib = 0; ib < BATCH; ++ib) {
            const float bce = s_acc[ib * 4 + 0];
            const float pc  = s_acc[ib * 4 + 1];
            const float bb  = s_acc[ib * 4 + 2];
            const float fo  = s_acc[ib * 4 + 3];
            sum_pc += pc;
            obj_l  += bce * (1.0f * pc + 0.5f * ((float)NANCH - pc));
            bbox_s += bb;
            cls_l  += fo / fmaxf(pc * (float)NCLS, 1.0f);
        }
        const float num_pos = fmaxf(sum_pc, 1.0f);
        out[0] = obj_l / (float)BATCH + 5.0f * bbox_s / num_pos + cls_l / (float)BATCH;
    }
}

extern "C" void kernel_launch(void* const* d_in, const int* in_sizes, int n_in,
                              void* d_out, int out_size, void* d_ws, size_t ws_size,
                              hipStream_t stream) {
    const float* obj   = (const float*)d_in[0];
    const float* boxes = (const float*)d_in[1];
    const float* cls   = (const float*)d_in[2];
    const float* tb    = (const float*)d_in[3];
    const int*   tl    = (const int*)d_in[4];
    float* out = (float*)d_out;

    // workspace: accums[32] floats @0 | counter @128
    float*        accums  = (float*)d_ws;
    unsigned int* counter = (unsigned int*)((char*)d_ws + 128);

    hipMemsetAsync(d_ws, 0, 132, stream);    // zero accums + counter

    dim3 gridA(NBLK, BATCH);
    anchor_kernel<<<gridA, 256, 0, stream>>>(obj, boxes, cls, tb, tl,
                                             accums, counter, out);
}

// Round 16
// 109.390 us; speedup vs baseline: 1.7292x; 1.7292x over previous
//
#include <hip/hip_runtime.h>
#include <math.h>

#define NCLS    80
#define MTGT    100
#define NANCH   19200   // 3*80*80
#define BATCH   8
#define BLKA    64                  // anchors per block
#define NBLK    (NANCH / BLKA)      // 300 blocks per image
#define NWAVE   4
#define TSLICE  (MTGT / NWAVE)      // 25 targets per wave
#define ROW4    (NCLS / 4)          // 20 float4 per class row

__device__ __forceinline__ float fast_rcp(float x) { return __builtin_amdgcn_rcpf(x); }

// focal-loss contribution of one class logit x (matches reference formula exactly)
__device__ __forceinline__ float focal_term(float x, bool is_t) {
    const float ax  = fabsf(x);
    const float q   = __expf(-ax);                        // e^{-|x|} in (0,1]
    const float ce0 = fmaxf(x, 0.0f) + __logf(1.0f + q);  // softplus(x) = ce for onehot=0
    const float r   = fast_rcp(1.0f + q);
    const float p   = (x >= 0.0f) ? r : q * r;            // sigmoid(x)
    const float pt  = is_t ? (1.0f - p) : p;              // 1 - p_t
    const float ce  = is_t ? (ce0 - x) : ce0;
    const float at  = is_t ? 0.25f : 0.75f;
    return at * pt * pt * ce;
}

// Pass 1: 256 threads / 64 anchors per block.
//   phase A: 4 waves scan 25-target slices, rcp-free cross-multiplied argmax
//   phase B: wave 0 merges, computes pos/BCE/GIoU, publishes posf/lab to LDS
//   phase C: ALL 4 waves cooperatively compute focal (coalesced, masked by posf)
// One float4 partial {bce,pos,bbox,focal} per block; every slot written every call.
__global__ __launch_bounds__(256) void anchor_kernel(
    const float* __restrict__ obj, const float* __restrict__ boxes,
    const float* __restrict__ cls, const float* __restrict__ tb,
    const int* __restrict__ tl, float4* __restrict__ partials)
{
    __shared__ float4 t_box[MTGT];    // (lo.x, lo.y, hi.x, hi.y)
    __shared__ float  t_area[MTGT];
    __shared__ int    t_lab[MTGT];
    __shared__ float  m_bi[NWAVE][BLKA];
    __shared__ float  m_bu[NWAVE][BLKA];
    __shared__ int    m_ix[NWAVE][BLKA];
    __shared__ float  s_posf[BLKA];
    __shared__ int    s_lab[BLKA];
    __shared__ float  s_foc[NWAVE];
    __shared__ float  s_bpb[3];       // wave0's reduced {bce, pos, bbox}

    const int b    = blockIdx.y;
    const int tid  = threadIdx.x;
    const int wave = tid >> 6;
    const int lane = tid & 63;

    if (tid < MTGT) {
        const float4 t = ((const float4*)tb)[b * MTGT + tid];
        t_box[tid]  = make_float4(t.x - 0.5f * t.z, t.y - 0.5f * t.w,
                                  t.x + 0.5f * t.z, t.y + 0.5f * t.w);
        t_area[tid] = t.z * t.w;
        t_lab[tid]  = tl[b * MTGT + tid];
    }
    __syncthreads();

    const int a0  = blockIdx.x * BLKA;         // first anchor of this block
    const int gid = b * NANCH + a0 + lane;

    const float4 bx = ((const float4*)boxes)[gid];
    const float lox = bx.x - 0.5f * bx.z, loy = bx.y - 0.5f * bx.w;
    const float hix = bx.x + 0.5f * bx.z, hiy = bx.y + 0.5f * bx.w;
    const float a1  = bx.z * bx.w;
    const float aa  = a1 + 1e-6f;              // fold union eps

    // phase A: rcp-free first-max argmax over this wave's target slice
    // iou_m > iou_best  <=>  inter_m*uni_best > inter_best*uni_m  (uni>0)
    float bi = -1.0f, bu = 1.0f; int bidx = 0;
    const int m0 = wave * TSLICE;
    #pragma unroll
    for (int mm = 0; mm < TSLICE; ++mm) {
        const int m = m0 + mm;
        const float4 t = t_box[m];
        float iw = fmaxf(fminf(hix, t.z) - fmaxf(lox, t.x), 0.0f);
        float ih = fmaxf(fminf(hiy, t.w) - fmaxf(loy, t.y), 0.0f);
        float inter = iw * ih;
        float uni   = aa + t_area[m] - inter;
        if (inter * bu > bi * uni) { bi = inter; bu = uni; bidx = m; }
    }
    m_bi[wave][lane] = bi;
    m_bu[wave][lane] = bu;
    m_ix[wave][lane] = bidx;
    __syncthreads();

    // phase B (wave 0): merge in ascending wave order (first-max preserved),
    // pos/BCE/GIoU, publish posf+label, reduce {bce,pos,bbox}
    if (wave == 0) {
        float Bi = m_bi[0][lane], Bu = m_bu[0][lane]; int Bx = m_ix[0][lane];
        #pragma unroll
        for (int w = 1; w < NWAVE; ++w) {
            const float ci = m_bi[w][lane], cu = m_bu[w][lane];
            if (ci * Bu > Bi * cu) { Bi = ci; Bu = cu; Bx = m_ix[w][lane]; }
        }

        const bool  pos  = (Bi + Bi >= Bu);   // iou >= 0.5 (Bu = uni + 1e-6)
        const float posf = pos ? 1.0f : 0.0f;
        s_posf[lane] = posf;
        s_lab[lane]  = t_lab[Bx];

        const float o   = obj[gid];
        const float bce = -fmaxf(__logf(pos ? o : 1.0f - o), -100.0f);

        float bbox_l = 0.0f;
        if (pos) {
            const float4 t   = t_box[Bx];
            const float uni  = a1 + t_area[Bx] - Bi;      // reference union (no eps)
            const float iou  = Bi * fast_rcp(Bu);
            const float ew   = fmaxf(fmaxf(hix, t.z) - fminf(lox, t.x), 0.0f);
            const float eh   = fmaxf(fmaxf(hiy, t.w) - fminf(loy, t.y), 0.0f);
            const float enc  = ew * eh;
            const float giou = iou - (enc - uni) * fast_rcp(enc + 1e-6f);
            bbox_l = 1.0f - giou;
        }

        float v0 = bce, v1 = posf, v2 = bbox_l;
        #pragma unroll
        for (int off = 32; off; off >>= 1) {
            v0 += __shfl_down(v0, off);
            v1 += __shfl_down(v1, off);
            v2 += __shfl_down(v2, off);
        }
        if (lane == 0) { s_bpb[0] = v0; s_bpb[1] = v1; s_bpb[2] = v2; }
    }
    __syncthreads();

    // phase C (all waves): cooperative focal. 64 anchors x 20 float4 = 1280
    // chunks flat across 256 threads x 5 iters; consecutive tids -> consecutive
    // 16-B addresses (coalesced). Negative anchors skipped via exec mask.
    float focal = 0.0f;
    #pragma unroll
    for (int k = 0; k < 5; ++k) {
        const int flat = k * 256 + tid;
        const int a    = flat / ROW4;          // anchor within block (0..63)
        const int j4   = flat - a * ROW4;      // float4 index within row (0..19)
        const float pf = s_posf[a];
        if (pf != 0.0f) {
            const int c = s_lab[a];
            const float4 v = *(const float4*)(cls +
                ((long)(b * NANCH + a0 + a)) * NCLS + j4 * 4);
            focal += focal_term(v.x, 4 * j4 + 0 == c)
                   + focal_term(v.y, 4 * j4 + 1 == c)
                   + focal_term(v.z, 4 * j4 + 2 == c)
                   + focal_term(v.w, 4 * j4 + 3 == c);
        }
    }
    #pragma unroll
    for (int off = 32; off; off >>= 1)
        focal += __shfl_down(focal, off);
    if (lane == 0) s_foc[wave] = focal;
    __syncthreads();

    if (tid == 0) {
        const float fsum = s_foc[0] + s_foc[1] + s_foc[2] + s_foc[3];
        partials[b * NBLK + blockIdx.x] =
            make_float4(s_bpb[0], s_bpb[1], s_bpb[2], fsum);
    }
}

// Pass 2: reduce 300 partials per image (one wave per image), apply reference formula.
__global__ __launch_bounds__(512) void finalize_kernel(
    const float4* __restrict__ partials, float* __restrict__ out)
{
    const int wave = threadIdx.x >> 6;   // image index 0..7
    const int lane = threadIdx.x & 63;

    float s0 = 0.f, s1 = 0.f, s2 = 0.f, s3 = 0.f;
    for (int blk = lane; blk < NBLK; blk += 64) {
        const float4 p = partials[wave * NBLK + blk];
        s0 += p.x; s1 += p.y; s2 += p.z; s3 += p.w;
    }
    #pragma unroll
    for (int off = 32; off; off >>= 1) {
        s0 += __shfl_down(s0, off);
        s1 += __shfl_down(s1, off);
        s2 += __shfl_down(s2, off);
        s3 += __shfl_down(s3, off);
    }
    __shared__ float img[BATCH][4];
    if (lane == 0) { img[wave][0] = s0; img[wave][1] = s1; img[wave][2] = s2; img[wave][3] = s3; }
    __syncthreads();
    if (threadIdx.x == 0) {
        float sum_pc = 0.f, obj_l = 0.f, bbox_s = 0.f, cls_l = 0.f;
        #pragma unroll
        for (int b = 0; b < BATCH; ++b) {
            const float bce = img[b][0];
            const float pc  = img[b][1];
            const float bb  = img[b][2];
            const float fo  = img[b][3];
            sum_pc += pc;
            obj_l  += bce * (1.0f * pc + 0.5f * ((float)NANCH - pc));
            bbox_s += bb;
            cls_l  += fo / fmaxf(pc * (float)NCLS, 1.0f);
        }
        const float num_pos = fmaxf(sum_pc, 1.0f);
        out[0] = obj_l / (float)BATCH + 5.0f * bbox_s / num_pos + cls_l / (float)BATCH;
    }
}

extern "C" void kernel_launch(void* const* d_in, const int* in_sizes, int n_in,
                              void* d_out, int out_size, void* d_ws, size_t ws_size,
                              hipStream_t stream) {
    const float* obj   = (const float*)d_in[0];
    const float* boxes = (const float*)d_in[1];
    const float* cls   = (const float*)d_in[2];
    const float* tb    = (const float*)d_in[3];
    const int*   tl    = (const int*)d_in[4];
    float* out = (float*)d_out;

    float4* partials = (float4*)d_ws;   // 8 images × 300 blocks × float4 = 38.4 KB

    dim3 gridA(NBLK, BATCH);
    anchor_kernel<<<gridA, 256, 0, stream>>>(obj, boxes, cls, tb, tl, partials);
    finalize_kernel<<<1, 512, 0, stream>>>(partials, out);
}